// Round 1
// baseline (704.744 us; speedup 1.0000x reference)
//
#include <hip/hip_runtime.h>

// ---------------------------------------------------------------------------
// MHA block: x[4,1024,2048], W*[2048,2048] (torch Linear: y = x @ W^T)
//   q,k,v = x@W{q,k,v}^T ; scores = q k^T * sqrt(128) (causal) ; softmax ;
//   ctx = attn @ v ; out = ctx @ Wo^T
// Strategy: f16 MFMA everywhere. Q/K path uses hi/lo f16 split (lo scaled by
// 2^11) for ~fp32-grade logits (softmax here is near-argmax: logit std ~100).
// ---------------------------------------------------------------------------

typedef _Float16 f16;
typedef _Float16 f16x8 __attribute__((ext_vector_type(8)));
typedef _Float16 f16x4 __attribute__((ext_vector_type(4)));
typedef float f32x4 __attribute__((ext_vector_type(4)));

__device__ __forceinline__ f32x4 mfma16(f16x8 a, f16x8 b, f32x4 c) {
  return __builtin_amdgcn_mfma_f32_16x16x32_f16(a, b, c, 0, 0, 0);
}

__device__ __forceinline__ void gld16(const void* g, void* l) {
  __builtin_amdgcn_global_load_lds(
      (const __attribute__((address_space(1))) void*)g,
      (__attribute__((address_space(3))) void*)l, 16, 0, 0);
}

static constexpr float LO_SCALE  = 2048.0f;   // 2^11
static constexpr float LO_INV    = 1.0f / 2048.0f;

// ---------------- conversion kernels ----------------
__global__ void conv_split_k(const float* __restrict__ src,
                             f16* __restrict__ hi, f16* __restrict__ lo, int n4) {
  int i = blockIdx.x * 256 + threadIdx.x;
  if (i >= n4) return;
  float4 v = reinterpret_cast<const float4*>(src)[i];
  f16x4 h, l;
  f16 t;
  t = (f16)v.x; h[0] = t; l[0] = (f16)((v.x - (float)t) * LO_SCALE);
  t = (f16)v.y; h[1] = t; l[1] = (f16)((v.y - (float)t) * LO_SCALE);
  t = (f16)v.z; h[2] = t; l[2] = (f16)((v.z - (float)t) * LO_SCALE);
  t = (f16)v.w; h[3] = t; l[3] = (f16)((v.w - (float)t) * LO_SCALE);
  reinterpret_cast<f16x4*>(hi)[i] = h;
  reinterpret_cast<f16x4*>(lo)[i] = l;
}

__global__ void conv_plain_k(const float* __restrict__ src, f16* __restrict__ dst, int n4) {
  int i = blockIdx.x * 256 + threadIdx.x;
  if (i >= n4) return;
  float4 v = reinterpret_cast<const float4*>(src)[i];
  f16x4 h;
  h[0] = (f16)v.x; h[1] = (f16)v.y; h[2] = (f16)v.z; h[3] = (f16)v.w;
  reinterpret_cast<f16x4*>(dst)[i] = h;
}

// ---------------- GEMM: C[M,N] = A[M,K] * B[N,K]^T ----------------
// 128x128 tile, BK=32, 256 threads (4 waves, 2x2 of 64x64), m97 2-barrier loop.
// SPLIT: A=(Ah+Al/2048), B=(Bh+Bl/2048), drop lo*lo; correction accumulator.
// OUTMODE: 0 = f16, 1 = split pair (hi + scaled lo), 2 = f32
template<bool SPLIT, int OUTMODE>
__global__ __launch_bounds__(256, 2) void gemm_bt(
    const f16* __restrict__ Ah, const f16* __restrict__ Al,
    const f16* __restrict__ Bh, const f16* __restrict__ Bl,
    void* __restrict__ C0, void* __restrict__ C1, int Mm, int Nn, int Kk)
{
  __shared__ f16 sAh[128 * 32];
  __shared__ f16 sBh[128 * 32];
  __shared__ f16 sAl[SPLIT ? 128 * 32 : 8];
  __shared__ f16 sBl[SPLIT ? 128 * 32 : 8];

  const int t = threadIdx.x;
  const int wave = t >> 6, lane = t & 63;
  const int l15 = lane & 15, lg = lane >> 4;
  const int wr = wave >> 1, wc = wave & 1;
  const long m0 = (long)blockIdx.y * 128, n0 = (long)blockIdx.x * 128;

  const int srow = t >> 2;            // 0..63
  const int scol = (t & 3) * 8;
  const long aoff = (m0 + srow) * (long)Kk + scol;
  const long boff = (n0 + srow) * (long)Kk + scol;
  const long rowstep = 64L * Kk;
  const int ldst = wave * 512;        // f16 elements, wave-uniform

  f32x4 acc[4][4] = {};
  f32x4 accc[SPLIT ? 4 : 1][SPLIT ? 4 : 1] = {};
  const int lof = l15 * 32 + lg * 8;

  for (int k0 = 0; k0 < Kk; k0 += 32) {
    gld16(Ah + aoff + k0,           sAh + ldst);
    gld16(Ah + aoff + rowstep + k0, sAh + 2048 + ldst);
    gld16(Bh + boff + k0,           sBh + ldst);
    gld16(Bh + boff + rowstep + k0, sBh + 2048 + ldst);
    if constexpr (SPLIT) {
      gld16(Al + aoff + k0,           sAl + ldst);
      gld16(Al + aoff + rowstep + k0, sAl + 2048 + ldst);
      gld16(Bl + boff + k0,           sBl + ldst);
      gld16(Bl + boff + rowstep + k0, sBl + 2048 + ldst);
    }
    __syncthreads();
    f16x8 a_h[4], b_h[4];
#pragma unroll
    for (int i = 0; i < 4; ++i) a_h[i] = *(const f16x8*)(sAh + (wr * 64 + i * 16) * 32 + lof);
#pragma unroll
    for (int j = 0; j < 4; ++j) b_h[j] = *(const f16x8*)(sBh + (wc * 64 + j * 16) * 32 + lof);
    if constexpr (SPLIT) {
      f16x8 a_l[4], b_l[4];
#pragma unroll
      for (int i = 0; i < 4; ++i) a_l[i] = *(const f16x8*)(sAl + (wr * 64 + i * 16) * 32 + lof);
#pragma unroll
      for (int j = 0; j < 4; ++j) b_l[j] = *(const f16x8*)(sBl + (wc * 64 + j * 16) * 32 + lof);
#pragma unroll
      for (int i = 0; i < 4; ++i)
#pragma unroll
        for (int j = 0; j < 4; ++j) {
          acc[i][j]  = mfma16(a_h[i], b_h[j], acc[i][j]);
          accc[i][j] = mfma16(a_h[i], b_l[j], accc[i][j]);
          accc[i][j] = mfma16(a_l[i], b_h[j], accc[i][j]);
        }
    } else {
#pragma unroll
      for (int i = 0; i < 4; ++i)
#pragma unroll
        for (int j = 0; j < 4; ++j)
          acc[i][j] = mfma16(a_h[i], b_h[j], acc[i][j]);
    }
    __syncthreads();
  }

#pragma unroll
  for (int i = 0; i < 4; ++i)
#pragma unroll
    for (int j = 0; j < 4; ++j)
#pragma unroll
      for (int r = 0; r < 4; ++r) {
        long row = m0 + wr * 64 + i * 16 + lg * 4 + r;
        long col = n0 + wc * 64 + j * 16 + l15;
        long idx = row * Nn + col;
        float v = acc[i][j][r];
        if constexpr (SPLIT) v += accc[i][j][r] * LO_INV;
        if constexpr (OUTMODE == 0) {
          ((f16*)C0)[idx] = (f16)v;
        } else if constexpr (OUTMODE == 1) {
          f16 hh = (f16)v;
          ((f16*)C0)[idx] = hh;
          ((f16*)C1)[idx] = (f16)((v - (float)hh) * LO_SCALE);
        } else {
          ((float*)C0)[idx] = v;
        }
      }
}

// ---------------- V transpose: V[b*1024+s][h*128+d] -> Vt[(b*16+h)*128+d][s] ---
__global__ void transpose_v_k(const f16* __restrict__ V, f16* __restrict__ Vt) {
  const int st = blockIdx.x;      // 16 s-tiles of 64
  const int dt = blockIdx.y;      // 2 d-tiles of 64
  const int bh = blockIdx.z;      // 64
  const int b = bh >> 4, h = bh & 15;
  __shared__ f16 tile[64][68];
  const int t = threadIdx.x;
  const int r = t >> 4;
  const int c4 = (t & 15) * 4;
#pragma unroll
  for (int p = 0; p < 4; ++p) {
    int row = r + p * 16;
    f16x4 v = *(const f16x4*)(V + (long)(b * 1024 + st * 64 + row) * 2048 + h * 128 + dt * 64 + c4);
    tile[row][c4] = v[0]; tile[row][c4 + 1] = v[1];
    tile[row][c4 + 2] = v[2]; tile[row][c4 + 3] = v[3];
  }
  __syncthreads();
#pragma unroll
  for (int p = 0; p < 4; ++p) {
    int drow = r + p * 16;
    f16x4 o;
    o[0] = tile[c4][drow]; o[1] = tile[c4 + 1][drow];
    o[2] = tile[c4 + 2][drow]; o[3] = tile[c4 + 3][drow];
    *(f16x4*)(Vt + ((long)bh * 128 + dt * 64 + drow) * 1024 + st * 64 + c4) = o;
  }
}

// ---------------- causal flash attention ----------------
// grid (8 q-tiles, 16 heads, 4 batch), 256 thr; wave owns 32 q-rows.
// scores: 3-pass split MFMA (K direct from L2); softmax wave-parallel in regs;
// P transposed via per-wave LDS; PV with pre-transposed V.
__global__ __launch_bounds__(256, 2) void attn_k(
    const f16* __restrict__ Qh, const f16* __restrict__ Ql,
    const f16* __restrict__ Kh, const f16* __restrict__ Kl,
    const f16* __restrict__ Vt, f16* __restrict__ Ctx)
{
  const int qt = blockIdx.x, h = blockIdx.y, b = blockIdx.z;
  const int t = threadIdx.x, wave = t >> 6, lane = t & 63;
  const int l15 = lane & 15, lg = lane >> 4;
  const int qbase = qt * 128 + wave * 32;

  __shared__ f16 pbuf[4][32 * 72];   // per-wave P^T staging, stride 72 (16B-aligned rows)

  const long qoff = (long)(b * 1024 + qbase) * 2048 + h * 128;
  f16x8 q_h[2][4], q_l[2][4];
#pragma unroll
  for (int i = 0; i < 2; ++i)
#pragma unroll
    for (int c = 0; c < 4; ++c) {
      long o8 = qoff + (long)(i * 16 + l15) * 2048 + c * 32 + lg * 8;
      q_h[i][c] = *(const f16x8*)(Qh + o8);
      q_l[i][c] = *(const f16x8*)(Ql + o8);
    }

  float mm[2][4], ll[2][4];
#pragma unroll
  for (int i = 0; i < 2; ++i)
#pragma unroll
    for (int r = 0; r < 4; ++r) { mm[i][r] = -1e30f; ll[i][r] = 0.f; }
  f32x4 o[2][8] = {};

  const long kbase = (long)(b * 1024) * 2048 + h * 128;
  const long vtb = (long)((b * 16 + h) * 128) * 1024;
  // softmax(scores * sqrt(128)) in exp2 domain: SC2 = sqrt(128)*log2(e)
  const float SC2 = (float)(11.313708498984761 * 1.4426950408889634);
  const int ntiles = 2 * qt + 2;   // uniform across waves (extra tiles fully masked)

  for (int kt = 0; kt < ntiles; ++kt) {
    const int k0 = kt * 64;
    f32x4 s[2][4] = {};
    f32x4 sc[2][4] = {};
#pragma unroll
    for (int c = 0; c < 4; ++c)
#pragma unroll
      for (int j = 0; j < 4; ++j) {
        long ko = kbase + (long)(k0 + j * 16 + l15) * 2048 + c * 32 + lg * 8;
        f16x8 kh = *(const f16x8*)(Kh + ko);
        f16x8 kl = *(const f16x8*)(Kl + ko);
#pragma unroll
        for (int i = 0; i < 2; ++i) {
          s[i][j]  = mfma16(q_h[i][c], kh, s[i][j]);
          sc[i][j] = mfma16(q_h[i][c], kl, sc[i][j]);
          sc[i][j] = mfma16(q_l[i][c], kh, sc[i][j]);
        }
      }
#pragma unroll
    for (int i = 0; i < 2; ++i)
#pragma unroll
      for (int j = 0; j < 4; ++j)
        s[i][j] = s[i][j] + sc[i][j] * LO_INV;
    if (k0 + 63 > qbase) {   // tile touches/crosses diagonal -> mask
#pragma unroll
      for (int i = 0; i < 2; ++i) {
        const int qrow = qbase + i * 16 + lg * 4;
#pragma unroll
        for (int j = 0; j < 4; ++j) {
          const int kcol = k0 + j * 16 + l15;
#pragma unroll
          for (int r = 0; r < 4; ++r)
            if (kcol > qrow + r) s[i][j][r] = -1e30f;
        }
      }
    }
#pragma unroll
    for (int i = 0; i < 2; ++i)
#pragma unroll
      for (int j = 0; j < 4; ++j)
        s[i][j] = s[i][j] * SC2;

#pragma unroll
    for (int i = 0; i < 2; ++i)
#pragma unroll
      for (int r = 0; r < 4; ++r) {
        float tm = fmaxf(fmaxf(s[i][0][r], s[i][1][r]), fmaxf(s[i][2][r], s[i][3][r]));
        tm = fmaxf(tm, __shfl_xor(tm, 1));
        tm = fmaxf(tm, __shfl_xor(tm, 2));
        tm = fmaxf(tm, __shfl_xor(tm, 4));
        tm = fmaxf(tm, __shfl_xor(tm, 8));
        float mn = fmaxf(mm[i][r], tm);
        float fac = __builtin_amdgcn_exp2f(mm[i][r] - mn);
        mm[i][r] = mn;
        float rs = 0.f;
#pragma unroll
        for (int j = 0; j < 4; ++j) {
          float p = __builtin_amdgcn_exp2f(s[i][j][r] - mn);
          rs += p;
          pbuf[wave][(i * 16 + lg * 4 + r) * 72 + j * 16 + l15] = (f16)p;
        }
        rs += __shfl_xor(rs, 1);
        rs += __shfl_xor(rs, 2);
        rs += __shfl_xor(rs, 4);
        rs += __shfl_xor(rs, 8);
        ll[i][r] = ll[i][r] * fac + rs;
#pragma unroll
        for (int n = 0; n < 8; ++n) o[i][n][r] *= fac;
      }
    __syncthreads();
#pragma unroll
    for (int kc = 0; kc < 2; ++kc) {
      f16x8 pa0 = *(const f16x8*)(&pbuf[wave][(0 + l15) * 72 + kc * 32 + lg * 8]);
      f16x8 pa1 = *(const f16x8*)(&pbuf[wave][(16 + l15) * 72 + kc * 32 + lg * 8]);
#pragma unroll
      for (int n = 0; n < 8; ++n) {
        f16x8 vv = *(const f16x8*)(Vt + vtb + (long)(n * 16 + l15) * 1024 + k0 + kc * 32 + lg * 8);
        o[0][n] = mfma16(pa0, vv, o[0][n]);
        o[1][n] = mfma16(pa1, vv, o[1][n]);
      }
    }
    __syncthreads();
  }

#pragma unroll
  for (int i = 0; i < 2; ++i)
#pragma unroll
    for (int r = 0; r < 4; ++r) {
      float inv = 1.0f / ll[i][r];
      long rbase = (long)(b * 1024 + qbase + i * 16 + lg * 4 + r) * 2048 + h * 128;
#pragma unroll
      for (int n = 0; n < 8; ++n)
        Ctx[rbase + n * 16 + l15] = (f16)(o[i][n][r] * inv);
    }
}

// ---------------- launch ----------------
extern "C" void kernel_launch(void* const* d_in, const int* in_sizes, int n_in,
                              void* d_out, int out_size, void* d_ws, size_t ws_size,
                              hipStream_t stream) {
  (void)in_sizes; (void)n_in; (void)out_size; (void)ws_size;
  const float* x  = (const float*)d_in[0];
  const float* Wq = (const float*)d_in[1];
  const float* Wk = (const float*)d_in[2];
  const float* Wv = (const float*)d_in[3];
  const float* Wo = (const float*)d_in[4];
  float* out = (float*)d_out;
  f16* ws = (f16*)d_ws;

  const long MD = 4096L * 2048;   // x / q / k / v / ctx elements
  const long DD = 2048L * 2048;   // weight elements

  f16* xh  = ws;                  // [MD]
  f16* xl  = ws + MD;             // [MD] (reused as V after projections)
  f16* wqh = ws + 2 * MD;         // [DD] x6 weights
  f16* wql = wqh + DD;
  f16* wkh = wql + DD;
  f16* wkl = wkh + DD;
  f16* wv  = wkl + DD;
  f16* wo  = wv + DD;
  f16* qh  = wo + DD;             // [MD] x4
  f16* ql  = qh + MD;
  f16* kh  = ql + MD;
  f16* kl  = kh + MD;
  f16* vt  = kl + MD;             // [MD] V^T
  f16* vh  = xl;                  // alias: V (plain), xl dead after K-proj
  f16* ctx = xh;                  // alias: ctx, xh dead after V-proj
  // total ws use: 14*MD + ... = 160 MiB

  conv_split_k<<<8192, 256, 0, stream>>>(x,  xh,  xl,  (int)(MD / 4));
  conv_split_k<<<4096, 256, 0, stream>>>(Wq, wqh, wql, (int)(DD / 4));
  conv_split_k<<<4096, 256, 0, stream>>>(Wk, wkh, wkl, (int)(DD / 4));
  conv_plain_k<<<4096, 256, 0, stream>>>(Wv, wv, (int)(DD / 4));
  conv_plain_k<<<4096, 256, 0, stream>>>(Wo, wo, (int)(DD / 4));

  dim3 gg(16, 32);  // (N/128, M/128)
  gemm_bt<true, 1><<<gg, 256, 0, stream>>>(xh, xl, wqh, wql, qh, ql, 4096, 2048, 2048);
  gemm_bt<true, 1><<<gg, 256, 0, stream>>>(xh, xl, wkh, wkl, kh, kl, 4096, 2048, 2048);
  gemm_bt<false, 0><<<gg, 256, 0, stream>>>(xh, nullptr, wv, nullptr, vh, nullptr, 4096, 2048, 2048);
  transpose_v_k<<<dim3(16, 2, 64), 256, 0, stream>>>(vh, vt);
  attn_k<<<dim3(8, 16, 4), 256, 0, stream>>>(qh, ql, kh, kl, vt, ctx);
  gemm_bt<false, 2><<<gg, 256, 0, stream>>>(ctx, nullptr, wo, nullptr, out, nullptr, 4096, 2048, 2048);
}

// Round 2
// 535.445 us; speedup vs baseline: 1.3162x; 1.3162x over previous
//
#include <hip/hip_runtime.h>

// ---------------------------------------------------------------------------
// MHA block: x[4,1024,2048], W*[2048,2048] (torch Linear: y = x @ W^T)
//   q,k,v = x@W{q,k,v}^T ; scores = q k^T * sqrt(128) (causal) ; softmax ;
//   ctx = attn @ v ; out = ctx @ Wo^T
// f16 MFMA everywhere; Q/K path hi/lo f16 split (lo scaled 2^11) for
// fp32-grade logits (softmax is near-argmax: logit std ~100).
// R1: attn rewritten — paired causal q-tiles (uniform work), LDS-staged K/V
// with XOR swizzle, XCD-aware grid so one head's blocks share an L2.
// ---------------------------------------------------------------------------

typedef _Float16 f16;
typedef _Float16 f16x8 __attribute__((ext_vector_type(8)));
typedef _Float16 f16x4 __attribute__((ext_vector_type(4)));
typedef float f32x4 __attribute__((ext_vector_type(4)));

__device__ __forceinline__ f32x4 mfma16(f16x8 a, f16x8 b, f32x4 c) {
  return __builtin_amdgcn_mfma_f32_16x16x32_f16(a, b, c, 0, 0, 0);
}

__device__ __forceinline__ void gld16(const void* g, void* l) {
  __builtin_amdgcn_global_load_lds(
      (const __attribute__((address_space(1))) void*)g,
      (__attribute__((address_space(3))) void*)l, 16, 0, 0);
}

static constexpr float LO_SCALE  = 2048.0f;   // 2^11
static constexpr float LO_INV    = 1.0f / 2048.0f;

// ---------------- conversion kernels ----------------
__global__ void conv_split_k(const float* __restrict__ src,
                             f16* __restrict__ hi, f16* __restrict__ lo, int n4) {
  int i = blockIdx.x * 256 + threadIdx.x;
  if (i >= n4) return;
  float4 v = reinterpret_cast<const float4*>(src)[i];
  f16x4 h, l;
  f16 t;
  t = (f16)v.x; h[0] = t; l[0] = (f16)((v.x - (float)t) * LO_SCALE);
  t = (f16)v.y; h[1] = t; l[1] = (f16)((v.y - (float)t) * LO_SCALE);
  t = (f16)v.z; h[2] = t; l[2] = (f16)((v.z - (float)t) * LO_SCALE);
  t = (f16)v.w; h[3] = t; l[3] = (f16)((v.w - (float)t) * LO_SCALE);
  reinterpret_cast<f16x4*>(hi)[i] = h;
  reinterpret_cast<f16x4*>(lo)[i] = l;
}

__global__ void conv_plain_k(const float* __restrict__ src, f16* __restrict__ dst, int n4) {
  int i = blockIdx.x * 256 + threadIdx.x;
  if (i >= n4) return;
  float4 v = reinterpret_cast<const float4*>(src)[i];
  f16x4 h;
  h[0] = (f16)v.x; h[1] = (f16)v.y; h[2] = (f16)v.z; h[3] = (f16)v.w;
  reinterpret_cast<f16x4*>(dst)[i] = h;
}

// ---------------- GEMM: C[M,N] = A[M,K] * B[N,K]^T ----------------
// 128x128 tile, BK=32, 256 threads (4 waves, 2x2 of 64x64), m97 2-barrier loop.
// SPLIT: A=(Ah+Al/2048), B=(Bh+Bl/2048), drop lo*lo; correction accumulator.
// OUTMODE: 0 = f16, 1 = split pair (hi + scaled lo), 2 = f32
template<bool SPLIT, int OUTMODE>
__global__ __launch_bounds__(256, 2) void gemm_bt(
    const f16* __restrict__ Ah, const f16* __restrict__ Al,
    const f16* __restrict__ Bh, const f16* __restrict__ Bl,
    void* __restrict__ C0, void* __restrict__ C1, int Mm, int Nn, int Kk)
{
  __shared__ f16 sAh[128 * 32];
  __shared__ f16 sBh[128 * 32];
  __shared__ f16 sAl[SPLIT ? 128 * 32 : 8];
  __shared__ f16 sBl[SPLIT ? 128 * 32 : 8];

  const int t = threadIdx.x;
  const int wave = t >> 6, lane = t & 63;
  const int l15 = lane & 15, lg = lane >> 4;
  const int wr = wave >> 1, wc = wave & 1;
  const long m0 = (long)blockIdx.y * 128, n0 = (long)blockIdx.x * 128;

  const int srow = t >> 2;            // 0..63
  const int scol = (t & 3) * 8;
  const long aoff = (m0 + srow) * (long)Kk + scol;
  const long boff = (n0 + srow) * (long)Kk + scol;
  const long rowstep = 64L * Kk;
  const int ldst = wave * 512;        // f16 elements, wave-uniform

  f32x4 acc[4][4] = {};
  f32x4 accc[SPLIT ? 4 : 1][SPLIT ? 4 : 1] = {};
  const int lof = l15 * 32 + lg * 8;

  for (int k0 = 0; k0 < Kk; k0 += 32) {
    gld16(Ah + aoff + k0,           sAh + ldst);
    gld16(Ah + aoff + rowstep + k0, sAh + 2048 + ldst);
    gld16(Bh + boff + k0,           sBh + ldst);
    gld16(Bh + boff + rowstep + k0, sBh + 2048 + ldst);
    if constexpr (SPLIT) {
      gld16(Al + aoff + k0,           sAl + ldst);
      gld16(Al + aoff + rowstep + k0, sAl + 2048 + ldst);
      gld16(Bl + boff + k0,           sBl + ldst);
      gld16(Bl + boff + rowstep + k0, sBl + 2048 + ldst);
    }
    __syncthreads();
    f16x8 a_h[4], b_h[4];
#pragma unroll
    for (int i = 0; i < 4; ++i) a_h[i] = *(const f16x8*)(sAh + (wr * 64 + i * 16) * 32 + lof);
#pragma unroll
    for (int j = 0; j < 4; ++j) b_h[j] = *(const f16x8*)(sBh + (wc * 64 + j * 16) * 32 + lof);
    if constexpr (SPLIT) {
      f16x8 a_l[4], b_l[4];
#pragma unroll
      for (int i = 0; i < 4; ++i) a_l[i] = *(const f16x8*)(sAl + (wr * 64 + i * 16) * 32 + lof);
#pragma unroll
      for (int j = 0; j < 4; ++j) b_l[j] = *(const f16x8*)(sBl + (wc * 64 + j * 16) * 32 + lof);
#pragma unroll
      for (int i = 0; i < 4; ++i)
#pragma unroll
        for (int j = 0; j < 4; ++j) {
          acc[i][j]  = mfma16(a_h[i], b_h[j], acc[i][j]);
          accc[i][j] = mfma16(a_h[i], b_l[j], accc[i][j]);
          accc[i][j] = mfma16(a_l[i], b_h[j], accc[i][j]);
        }
    } else {
#pragma unroll
      for (int i = 0; i < 4; ++i)
#pragma unroll
        for (int j = 0; j < 4; ++j)
          acc[i][j] = mfma16(a_h[i], b_h[j], acc[i][j]);
    }
    __syncthreads();
  }

#pragma unroll
  for (int i = 0; i < 4; ++i)
#pragma unroll
    for (int j = 0; j < 4; ++j)
#pragma unroll
      for (int r = 0; r < 4; ++r) {
        long row = m0 + wr * 64 + i * 16 + lg * 4 + r;
        long col = n0 + wc * 64 + j * 16 + l15;
        long idx = row * Nn + col;
        float v = acc[i][j][r];
        if constexpr (SPLIT) v += accc[i][j][r] * LO_INV;
        if constexpr (OUTMODE == 0) {
          ((f16*)C0)[idx] = (f16)v;
        } else if constexpr (OUTMODE == 1) {
          f16 hh = (f16)v;
          ((f16*)C0)[idx] = hh;
          ((f16*)C1)[idx] = (f16)((v - (float)hh) * LO_SCALE);
        } else {
          ((float*)C0)[idx] = v;
        }
      }
}

// ---------------- V transpose: V[b*1024+s][h*128+d] -> Vt[(b*16+h)*128+d][s] ---
__global__ void transpose_v_k(const f16* __restrict__ V, f16* __restrict__ Vt) {
  const int st = blockIdx.x;      // 16 s-tiles of 64
  const int dt = blockIdx.y;      // 2 d-tiles of 64
  const int bh = blockIdx.z;      // 64
  const int b = bh >> 4, h = bh & 15;
  __shared__ f16 tile[64][68];
  const int t = threadIdx.x;
  const int r = t >> 4;
  const int c4 = (t & 15) * 4;
#pragma unroll
  for (int p = 0; p < 4; ++p) {
    int row = r + p * 16;
    f16x4 v = *(const f16x4*)(V + (long)(b * 1024 + st * 64 + row) * 2048 + h * 128 + dt * 64 + c4);
    tile[row][c4] = v[0]; tile[row][c4 + 1] = v[1];
    tile[row][c4 + 2] = v[2]; tile[row][c4 + 3] = v[3];
  }
  __syncthreads();
#pragma unroll
  for (int p = 0; p < 4; ++p) {
    int drow = r + p * 16;
    f16x4 o;
    o[0] = tile[c4][drow]; o[1] = tile[c4 + 1][drow];
    o[2] = tile[c4 + 2][drow]; o[3] = tile[c4 + 3][drow];
    *(f16x4*)(Vt + ((long)bh * 128 + dt * 64 + drow) * 1024 + st * 64 + c4) = o;
  }
}

// ---------------- causal flash attention (R1 rewrite) ----------------
// grid (64 = h*4+b groups, 8 = p), 256 thr / 4 waves; each wave owns 16 q-rows.
// Block p processes q-tiles (15-p) then (p): uniform 17 k-tiles per block.
// blockIdx.x = group  ->  XCD = linear_bid % 8 = group % 8: all 8 p-blocks of
// one (b,h) share an XCD's L2 for K/V.
// K(hi,lo) and V staged in LDS via global_load_lds w=16, XOR-swizzled
// (byte ^= (row&7)<<4) -> conflict-free ds_read_b128; staged once per block
// instead of 4x redundant per-wave global reads.
__global__ __launch_bounds__(256, 2) void attn_k(
    const f16* __restrict__ Qh, const f16* __restrict__ Ql,
    const f16* __restrict__ Kh, const f16* __restrict__ Kl,
    const f16* __restrict__ Vt, f16* __restrict__ Ctx)
{
  const int g = blockIdx.x;           // h*4 + b
  const int p = blockIdx.y;           // 0..7
  const int b = g & 3, h = g >> 2;
  const int t = threadIdx.x, wave = t >> 6, lane = t & 63;
  const int l15 = lane & 15, lg = lane >> 4;

  __shared__ f16 sKh[64 * 128];       // [krow][d], swizzled
  __shared__ f16 sKl[64 * 128];
  __shared__ f16 sV [128 * 64];       // [d][s], swizzled
  __shared__ f16 pbuf[4][16 * 72];    // per-wave P^T staging

  const long kbase = (long)(b * 1024) * 2048 + h * 128;
  const long vtb = (long)((b * 16 + h) * 128) * 1024;
  // softmax(scores * sqrt(128)) in exp2 domain: SC2 = sqrt(128)*log2(e)
  const float SC2 = (float)(11.313708498984761 * 1.4426950408889634);

  // staging index precompute (swizzled global source, linear LDS dest)
  const int krow_s = t >> 4;                       // + q*16
  const int vrow_s = t >> 3;                       // + q*32

#pragma unroll
  for (int half = 0; half < 2; ++half) {
    const int myqt = half ? p : 15 - p;
    const int qbase = myqt * 64 + wave * 16;

    // Q fragments (hi/lo) into registers
    f16x8 q_h[4], q_l[4];
#pragma unroll
    for (int c = 0; c < 4; ++c) {
      long o8 = (long)(b * 1024 + qbase + l15) * 2048 + h * 128 + c * 32 + lg * 8;
      q_h[c] = *(const f16x8*)(Qh + o8);
      q_l[c] = *(const f16x8*)(Ql + o8);
    }

    float mm[4], ll[4];
#pragma unroll
    for (int r = 0; r < 4; ++r) { mm[r] = -1e30f; ll[r] = 0.f; }
    f32x4 o[8] = {};

    const int nt = myqt + 1;
    for (int kt = 0; kt < nt; ++kt) {
      const int k0 = kt * 64;
      // ---- stage K (hi,lo) [64][128] and V [128][64] into LDS, swizzled ----
#pragma unroll
      for (int q = 0; q < 4; ++q) {
        const int row = q * 16 + krow_s;
        const int colx = ((t & 15) * 8) ^ ((row & 7) << 3);
        gld16(Kh + kbase + (long)(k0 + row) * 2048 + colx, sKh + q * 2048 + t * 8);
        gld16(Kl + kbase + (long)(k0 + row) * 2048 + colx, sKl + q * 2048 + t * 8);
      }
#pragma unroll
      for (int q = 0; q < 4; ++q) {
        const int row = q * 32 + vrow_s;
        const int colx = ((t & 7) * 8) ^ ((row & 7) << 3);
        gld16(Vt + vtb + (long)row * 1024 + k0 + colx, sV + q * 2048 + t * 8);
      }
      __syncthreads();

      // ---- QK^T (3-pass split) ----
      f32x4 s[4] = {};
      f32x4 sc[4] = {};
#pragma unroll
      for (int c = 0; c < 4; ++c)
#pragma unroll
        for (int j = 0; j < 4; ++j) {
          const int krow = j * 16 + l15;
          const int koff = krow * 128 + (((c * 32 + lg * 8)) ^ ((krow & 7) << 3));
          f16x8 kh = *(const f16x8*)(sKh + koff);
          f16x8 kl = *(const f16x8*)(sKl + koff);
          s[j]  = mfma16(q_h[c], kh, s[j]);
          sc[j] = mfma16(q_h[c], kl, sc[j]);
          sc[j] = mfma16(q_l[c], kh, sc[j]);
        }
#pragma unroll
      for (int j = 0; j < 4; ++j)
        s[j] = s[j] + sc[j] * LO_INV;

      if (k0 + 63 > qbase) {   // tile touches/crosses diagonal -> mask
        const int qrow = qbase + lg * 4;
#pragma unroll
        for (int j = 0; j < 4; ++j) {
          const int kcol = k0 + j * 16 + l15;
#pragma unroll
          for (int r = 0; r < 4; ++r)
            if (kcol > qrow + r) s[j][r] = -1e30f;
        }
      }
#pragma unroll
      for (int j = 0; j < 4; ++j)
        s[j] = s[j] * SC2;

      // ---- online softmax (wave-parallel over 16-lane groups) ----
#pragma unroll
      for (int r = 0; r < 4; ++r) {
        float tm = fmaxf(fmaxf(s[0][r], s[1][r]), fmaxf(s[2][r], s[3][r]));
        tm = fmaxf(tm, __shfl_xor(tm, 1));
        tm = fmaxf(tm, __shfl_xor(tm, 2));
        tm = fmaxf(tm, __shfl_xor(tm, 4));
        tm = fmaxf(tm, __shfl_xor(tm, 8));
        float mn = fmaxf(mm[r], tm);
        float fac = __builtin_amdgcn_exp2f(mm[r] - mn);
        mm[r] = mn;
        float rs = 0.f;
#pragma unroll
        for (int j = 0; j < 4; ++j) {
          float pv = __builtin_amdgcn_exp2f(s[j][r] - mn);
          rs += pv;
          pbuf[wave][(lg * 4 + r) * 72 + j * 16 + l15] = (f16)pv;
        }
        rs += __shfl_xor(rs, 1);
        rs += __shfl_xor(rs, 2);
        rs += __shfl_xor(rs, 4);
        rs += __shfl_xor(rs, 8);
        ll[r] = ll[r] * fac + rs;
#pragma unroll
        for (int n = 0; n < 8; ++n) o[n][r] *= fac;
      }
      __syncthreads();

      // ---- PV ----
#pragma unroll
      for (int kc = 0; kc < 2; ++kc) {
        f16x8 pa = *(const f16x8*)(&pbuf[wave][l15 * 72 + kc * 32 + lg * 8]);
#pragma unroll
        for (int n = 0; n < 8; ++n) {
          const int vrow = n * 16 + l15;
          f16x8 vv = *(const f16x8*)(sV + vrow * 64 + (((kc * 32 + lg * 8)) ^ ((vrow & 7) << 3)));
          o[n] = mfma16(pa, vv, o[n]);
        }
      }
      __syncthreads();
    }

    // ---- epilogue ----
#pragma unroll
    for (int r = 0; r < 4; ++r) {
      float inv = 1.0f / ll[r];
      long rbase = (long)(b * 1024 + qbase + lg * 4 + r) * 2048 + h * 128;
#pragma unroll
      for (int n = 0; n < 8; ++n)
        Ctx[rbase + n * 16 + l15] = (f16)(o[n][r] * inv);
    }
  }
}

// ---------------- launch ----------------
extern "C" void kernel_launch(void* const* d_in, const int* in_sizes, int n_in,
                              void* d_out, int out_size, void* d_ws, size_t ws_size,
                              hipStream_t stream) {
  (void)in_sizes; (void)n_in; (void)out_size; (void)ws_size;
  const float* x  = (const float*)d_in[0];
  const float* Wq = (const float*)d_in[1];
  const float* Wk = (const float*)d_in[2];
  const float* Wv = (const float*)d_in[3];
  const float* Wo = (const float*)d_in[4];
  float* out = (float*)d_out;
  f16* ws = (f16*)d_ws;

  const long MD = 4096L * 2048;   // x / q / k / v / ctx elements
  const long DD = 2048L * 2048;   // weight elements

  f16* xh  = ws;                  // [MD]
  f16* xl  = ws + MD;             // [MD] (reused as V after projections)
  f16* wqh = ws + 2 * MD;         // [DD] x6 weights
  f16* wql = wqh + DD;
  f16* wkh = wql + DD;
  f16* wkl = wkh + DD;
  f16* wv  = wkl + DD;
  f16* wo  = wv + DD;
  f16* qh  = wo + DD;             // [MD] x4
  f16* ql  = qh + MD;
  f16* kh  = ql + MD;
  f16* kl  = kh + MD;
  f16* vt  = kl + MD;             // [MD] V^T
  f16* vh  = xl;                  // alias: V (plain), xl dead after K-proj
  f16* ctx = xh;                  // alias: ctx, xh dead after V-proj

  conv_split_k<<<8192, 256, 0, stream>>>(x,  xh,  xl,  (int)(MD / 4));
  conv_split_k<<<4096, 256, 0, stream>>>(Wq, wqh, wql, (int)(DD / 4));
  conv_split_k<<<4096, 256, 0, stream>>>(Wk, wkh, wkl, (int)(DD / 4));
  conv_plain_k<<<4096, 256, 0, stream>>>(Wv, wv, (int)(DD / 4));
  conv_plain_k<<<4096, 256, 0, stream>>>(Wo, wo, (int)(DD / 4));

  dim3 gg(16, 32);  // (N/128, M/128)
  gemm_bt<true, 1><<<gg, 256, 0, stream>>>(xh, xl, wqh, wql, qh, ql, 4096, 2048, 2048);
  gemm_bt<true, 1><<<gg, 256, 0, stream>>>(xh, xl, wkh, wkl, kh, kl, 4096, 2048, 2048);
  gemm_bt<false, 0><<<gg, 256, 0, stream>>>(xh, nullptr, wv, nullptr, vh, nullptr, 4096, 2048, 2048);
  transpose_v_k<<<dim3(16, 2, 64), 256, 0, stream>>>(vh, vt);
  attn_k<<<dim3(64, 8), 256, 0, stream>>>(qh, ql, kh, kl, vt, ctx);
  gemm_bt<false, 2><<<gg, 256, 0, stream>>>(ctx, nullptr, wo, nullptr, out, nullptr, 4096, 2048, 2048);
}

// Round 3
// 533.979 us; speedup vs baseline: 1.3198x; 1.0027x over previous
//
#include <hip/hip_runtime.h>

// ---------------------------------------------------------------------------
// MHA block: x[4,1024,2048], W*[2048,2048] (torch Linear: y = x @ W^T)
//   q,k,v = x@W{q,k,v}^T ; scores = q k^T * sqrt(128) (causal) ; softmax ;
//   ctx = attn @ v ; out = ctx @ Wo^T
// f16 MFMA everywhere; Q/K path hi/lo f16 split (lo scaled 2^11) for
// fp32-grade logits (softmax is near-argmax: logit std ~100).
// R2: split GEMM rewritten with T2 XOR-swizzled LDS ([128][64] interleaved
// hi|lo tiles, row stride 128B = bank wrap) -> conflict-free ds_read_b128.
// ---------------------------------------------------------------------------

typedef _Float16 f16;
typedef _Float16 f16x8 __attribute__((ext_vector_type(8)));
typedef _Float16 f16x4 __attribute__((ext_vector_type(4)));
typedef float f32x4 __attribute__((ext_vector_type(4)));

__device__ __forceinline__ f32x4 mfma16(f16x8 a, f16x8 b, f32x4 c) {
  return __builtin_amdgcn_mfma_f32_16x16x32_f16(a, b, c, 0, 0, 0);
}

__device__ __forceinline__ void gld16(const void* g, void* l) {
  __builtin_amdgcn_global_load_lds(
      (const __attribute__((address_space(1))) void*)g,
      (__attribute__((address_space(3))) void*)l, 16, 0, 0);
}

static constexpr float LO_SCALE  = 2048.0f;   // 2^11
static constexpr float LO_INV    = 1.0f / 2048.0f;

// ---------------- conversion kernels ----------------
__global__ void conv_split_k(const float* __restrict__ src,
                             f16* __restrict__ hi, f16* __restrict__ lo, int n4) {
  int i = blockIdx.x * 256 + threadIdx.x;
  if (i >= n4) return;
  float4 v = reinterpret_cast<const float4*>(src)[i];
  f16x4 h, l;
  f16 t;
  t = (f16)v.x; h[0] = t; l[0] = (f16)((v.x - (float)t) * LO_SCALE);
  t = (f16)v.y; h[1] = t; l[1] = (f16)((v.y - (float)t) * LO_SCALE);
  t = (f16)v.z; h[2] = t; l[2] = (f16)((v.z - (float)t) * LO_SCALE);
  t = (f16)v.w; h[3] = t; l[3] = (f16)((v.w - (float)t) * LO_SCALE);
  reinterpret_cast<f16x4*>(hi)[i] = h;
  reinterpret_cast<f16x4*>(lo)[i] = l;
}

__global__ void conv_plain_k(const float* __restrict__ src, f16* __restrict__ dst, int n4) {
  int i = blockIdx.x * 256 + threadIdx.x;
  if (i >= n4) return;
  float4 v = reinterpret_cast<const float4*>(src)[i];
  f16x4 h;
  h[0] = (f16)v.x; h[1] = (f16)v.y; h[2] = (f16)v.z; h[3] = (f16)v.w;
  reinterpret_cast<f16x4*>(dst)[i] = h;
}

// ---------------- plain GEMM: C[M,N] = A[M,K] * B[N,K]^T ----------------
// 128x128 tile, BK=32, 256 threads (4 waves, 2x2 of 64x64), m97 2-barrier loop.
// OUTMODE: 0 = f16, 2 = f32
template<int OUTMODE>
__global__ __launch_bounds__(256, 2) void gemm_bt(
    const f16* __restrict__ Ah, const f16* __restrict__ Bh,
    void* __restrict__ C0, int Nn, int Kk)
{
  __shared__ f16 sAh[128 * 32];
  __shared__ f16 sBh[128 * 32];

  const int t = threadIdx.x;
  const int wave = t >> 6, lane = t & 63;
  const int l15 = lane & 15, lg = lane >> 4;
  const int wr = wave >> 1, wc = wave & 1;
  const long m0 = (long)blockIdx.y * 128, n0 = (long)blockIdx.x * 128;

  const int srow = t >> 2;            // 0..63
  const int scol = (t & 3) * 8;
  const long aoff = (m0 + srow) * (long)Kk + scol;
  const long boff = (n0 + srow) * (long)Kk + scol;
  const long rowstep = 64L * Kk;
  const int ldst = wave * 512;        // f16 elements, wave-uniform

  f32x4 acc[4][4] = {};
  const int lof = l15 * 32 + lg * 8;

  for (int k0 = 0; k0 < Kk; k0 += 32) {
    gld16(Ah + aoff + k0,           sAh + ldst);
    gld16(Ah + aoff + rowstep + k0, sAh + 2048 + ldst);
    gld16(Bh + boff + k0,           sBh + ldst);
    gld16(Bh + boff + rowstep + k0, sBh + 2048 + ldst);
    __syncthreads();
    f16x8 a_h[4], b_h[4];
#pragma unroll
    for (int i = 0; i < 4; ++i) a_h[i] = *(const f16x8*)(sAh + (wr * 64 + i * 16) * 32 + lof);
#pragma unroll
    for (int j = 0; j < 4; ++j) b_h[j] = *(const f16x8*)(sBh + (wc * 64 + j * 16) * 32 + lof);
#pragma unroll
    for (int i = 0; i < 4; ++i)
#pragma unroll
      for (int j = 0; j < 4; ++j)
        acc[i][j] = mfma16(a_h[i], b_h[j], acc[i][j]);
    __syncthreads();
  }

#pragma unroll
  for (int i = 0; i < 4; ++i)
#pragma unroll
    for (int j = 0; j < 4; ++j)
#pragma unroll
      for (int r = 0; r < 4; ++r) {
        long row = m0 + wr * 64 + i * 16 + lg * 4 + r;
        long col = n0 + wc * 64 + j * 16 + l15;
        long idx = row * Nn + col;
        float v = acc[i][j][r];
        if constexpr (OUTMODE == 0) {
          ((f16*)C0)[idx] = (f16)v;
        } else {
          ((float*)C0)[idx] = v;
        }
      }
}

// ---------------- split GEMM: C = (Ah+Al/2048)(Bh+Bl/2048)^T, drop lo*lo ----
// 128x128 tile, BK=32. LDS tiles [128 rows][64 f16 = 128B]: cols 0..31 = hi,
// 32..63 = lo, XOR-swizzled byte ^= ((row&7)<<4). Row stride 128B = exact
// 32-bank wrap -> per-16-lane-quarter banks = 4*(lg ^ (l15&7)): conflict-free.
// Staging: linear LDS dest (gld16 requirement) + inverse-swizzled per-lane
// global source (hi/lo buffer chosen per lane).
__global__ __launch_bounds__(256, 2) void gemm_split(
    const f16* __restrict__ Ah, const f16* __restrict__ Al,
    const f16* __restrict__ Bh, const f16* __restrict__ Bl,
    f16* __restrict__ Chi, f16* __restrict__ Clo, int Nn, int Kk)
{
  __shared__ f16 sA[128 * 64];
  __shared__ f16 sB[128 * 64];

  const int t = threadIdx.x;
  const int wave = t >> 6, lane = t & 63;
  const int l15 = lane & 15, lg = lane >> 4;
  const int wr = wave >> 1, wc = wave & 1;
  const long m0 = (long)blockIdx.y * 128, n0 = (long)blockIdx.x * 128;

  // ---- staging precompute: thread t writes 16B at phys byte (q*4096 + t*16)
  // phys row = q*32 + (t>>3); within-row phys byte = (t&7)*16.
  // logical byte = phys ^ ((row&7)<<4); logical f16 col 0..63 -> hi/lo + k.
  const int srow = t >> 3;                                  // + q*32
  const int colf16 = ((((t & 7) * 16) ^ ((srow & 7) << 4)) >> 1); // 0..63
  const int kcol = colf16 & 31;
  const bool islo = colf16 >= 32;
  const f16* srcA = islo ? Al : Ah;
  const f16* srcB = islo ? Bl : Bh;
  const long aoff = (m0 + srow) * (long)Kk + kcol;
  const long boff = (n0 + srow) * (long)Kk + kcol;
  const long qstep = 32L * Kk;        // block-uniform
  const int dstbase = t * 8;          // f16, + q*2048

  // ---- read precompute: frag row = base16 + l15 (base16 % 16 == 0)
  const int r7 = (l15 & 7) << 4;                 // row-XOR bits (bytes)
  const int ch = ((lg * 16) ^ r7) >> 1;          // hi frag col (f16)
  const int cl = ((64 + lg * 16) ^ r7) >> 1;     // lo frag col (f16)

  f32x4 acc[4][4] = {};
  f32x4 accc[4][4] = {};

  for (int k0 = 0; k0 < Kk; k0 += 32) {
#pragma unroll
    for (int q = 0; q < 4; ++q) {
      gld16(srcA + aoff + q * qstep + k0, sA + q * 2048 + dstbase);
      gld16(srcB + boff + q * qstep + k0, sB + q * 2048 + dstbase);
    }
    __syncthreads();
    f16x8 a_h[4], a_l[4], b_h[4], b_l[4];
#pragma unroll
    for (int i = 0; i < 4; ++i) {
      const int row = wr * 64 + i * 16 + l15;
      a_h[i] = *(const f16x8*)(sA + row * 64 + ch);
      a_l[i] = *(const f16x8*)(sA + row * 64 + cl);
    }
#pragma unroll
    for (int j = 0; j < 4; ++j) {
      const int row = wc * 64 + j * 16 + l15;
      b_h[j] = *(const f16x8*)(sB + row * 64 + ch);
      b_l[j] = *(const f16x8*)(sB + row * 64 + cl);
    }
#pragma unroll
    for (int i = 0; i < 4; ++i)
#pragma unroll
      for (int j = 0; j < 4; ++j) {
        acc[i][j]  = mfma16(a_h[i], b_h[j], acc[i][j]);
        accc[i][j] = mfma16(a_h[i], b_l[j], accc[i][j]);
        accc[i][j] = mfma16(a_l[i], b_h[j], accc[i][j]);
      }
    __syncthreads();
  }

#pragma unroll
  for (int i = 0; i < 4; ++i)
#pragma unroll
    for (int j = 0; j < 4; ++j)
#pragma unroll
      for (int r = 0; r < 4; ++r) {
        long row = m0 + wr * 64 + i * 16 + lg * 4 + r;
        long col = n0 + wc * 64 + j * 16 + l15;
        long idx = row * Nn + col;
        float v = acc[i][j][r] + accc[i][j][r] * LO_INV;
        f16 hh = (f16)v;
        Chi[idx] = hh;
        Clo[idx] = (f16)((v - (float)hh) * LO_SCALE);
      }
}

// ---------------- V transpose: V[b*1024+s][h*128+d] -> Vt[(b*16+h)*128+d][s] ---
__global__ void transpose_v_k(const f16* __restrict__ V, f16* __restrict__ Vt) {
  const int st = blockIdx.x;      // 16 s-tiles of 64
  const int dt = blockIdx.y;      // 2 d-tiles of 64
  const int bh = blockIdx.z;      // 64
  const int b = bh >> 4, h = bh & 15;
  __shared__ f16 tile[64][68];
  const int t = threadIdx.x;
  const int r = t >> 4;
  const int c4 = (t & 15) * 4;
#pragma unroll
  for (int p = 0; p < 4; ++p) {
    int row = r + p * 16;
    f16x4 v = *(const f16x4*)(V + (long)(b * 1024 + st * 64 + row) * 2048 + h * 128 + dt * 64 + c4);
    tile[row][c4] = v[0]; tile[row][c4 + 1] = v[1];
    tile[row][c4 + 2] = v[2]; tile[row][c4 + 3] = v[3];
  }
  __syncthreads();
#pragma unroll
  for (int p = 0; p < 4; ++p) {
    int drow = r + p * 16;
    f16x4 o;
    o[0] = tile[c4][drow]; o[1] = tile[c4 + 1][drow];
    o[2] = tile[c4 + 2][drow]; o[3] = tile[c4 + 3][drow];
    *(f16x4*)(Vt + ((long)bh * 128 + dt * 64 + drow) * 1024 + st * 64 + c4) = o;
  }
}

// ---------------- causal flash attention ----------------
// grid (64 = h*4+b groups, 8 = p), 256 thr / 4 waves; each wave owns 16 q-rows.
// Block p processes q-tiles (15-p) then (p): uniform 17 k-tiles per block.
// K(hi,lo) and V staged in LDS via gld16, XOR-swizzled.
__global__ __launch_bounds__(256, 2) void attn_k(
    const f16* __restrict__ Qh, const f16* __restrict__ Ql,
    const f16* __restrict__ Kh, const f16* __restrict__ Kl,
    const f16* __restrict__ Vt, f16* __restrict__ Ctx)
{
  const int g = blockIdx.x;           // h*4 + b
  const int p = blockIdx.y;           // 0..7
  const int b = g & 3, h = g >> 2;
  const int t = threadIdx.x, wave = t >> 6, lane = t & 63;
  const int l15 = lane & 15, lg = lane >> 4;

  __shared__ f16 sKh[64 * 128];       // [krow][d], swizzled
  __shared__ f16 sKl[64 * 128];
  __shared__ f16 sV [128 * 64];       // [d][s], swizzled
  __shared__ f16 pbuf[4][16 * 72];    // per-wave P^T staging

  const long kbase = (long)(b * 1024) * 2048 + h * 128;
  const long vtb = (long)((b * 16 + h) * 128) * 1024;
  const float SC2 = (float)(11.313708498984761 * 1.4426950408889634);

  const int krow_s = t >> 4;                       // + q*16
  const int vrow_s = t >> 3;                       // + q*32

#pragma unroll
  for (int half = 0; half < 2; ++half) {
    const int myqt = half ? p : 15 - p;
    const int qbase = myqt * 64 + wave * 16;

    f16x8 q_h[4], q_l[4];
#pragma unroll
    for (int c = 0; c < 4; ++c) {
      long o8 = (long)(b * 1024 + qbase + l15) * 2048 + h * 128 + c * 32 + lg * 8;
      q_h[c] = *(const f16x8*)(Qh + o8);
      q_l[c] = *(const f16x8*)(Ql + o8);
    }

    float mm[4], ll[4];
#pragma unroll
    for (int r = 0; r < 4; ++r) { mm[r] = -1e30f; ll[r] = 0.f; }
    f32x4 o[8] = {};

    const int nt = myqt + 1;
    for (int kt = 0; kt < nt; ++kt) {
      const int k0 = kt * 64;
#pragma unroll
      for (int q = 0; q < 4; ++q) {
        const int row = q * 16 + krow_s;
        const int colx = ((t & 15) * 8) ^ ((row & 7) << 3);
        gld16(Kh + kbase + (long)(k0 + row) * 2048 + colx, sKh + q * 2048 + t * 8);
        gld16(Kl + kbase + (long)(k0 + row) * 2048 + colx, sKl + q * 2048 + t * 8);
      }
#pragma unroll
      for (int q = 0; q < 4; ++q) {
        const int row = q * 32 + vrow_s;
        const int colx = ((t & 7) * 8) ^ ((row & 7) << 3);
        gld16(Vt + vtb + (long)row * 1024 + k0 + colx, sV + q * 2048 + t * 8);
      }
      __syncthreads();

      f32x4 s[4] = {};
      f32x4 sc[4] = {};
#pragma unroll
      for (int c = 0; c < 4; ++c)
#pragma unroll
        for (int j = 0; j < 4; ++j) {
          const int krow = j * 16 + l15;
          const int koff = krow * 128 + (((c * 32 + lg * 8)) ^ ((krow & 7) << 3));
          f16x8 kh = *(const f16x8*)(sKh + koff);
          f16x8 kl = *(const f16x8*)(sKl + koff);
          s[j]  = mfma16(q_h[c], kh, s[j]);
          sc[j] = mfma16(q_h[c], kl, sc[j]);
          sc[j] = mfma16(q_l[c], kh, sc[j]);
        }
#pragma unroll
      for (int j = 0; j < 4; ++j)
        s[j] = s[j] + sc[j] * LO_INV;

      if (k0 + 63 > qbase) {
        const int qrow = qbase + lg * 4;
#pragma unroll
        for (int j = 0; j < 4; ++j) {
          const int kcol = k0 + j * 16 + l15;
#pragma unroll
          for (int r = 0; r < 4; ++r)
            if (kcol > qrow + r) s[j][r] = -1e30f;
        }
      }
#pragma unroll
      for (int j = 0; j < 4; ++j)
        s[j] = s[j] * SC2;

#pragma unroll
      for (int r = 0; r < 4; ++r) {
        float tm = fmaxf(fmaxf(s[0][r], s[1][r]), fmaxf(s[2][r], s[3][r]));
        tm = fmaxf(tm, __shfl_xor(tm, 1));
        tm = fmaxf(tm, __shfl_xor(tm, 2));
        tm = fmaxf(tm, __shfl_xor(tm, 4));
        tm = fmaxf(tm, __shfl_xor(tm, 8));
        float mn = fmaxf(mm[r], tm);
        float fac = __builtin_amdgcn_exp2f(mm[r] - mn);
        mm[r] = mn;
        float rs = 0.f;
#pragma unroll
        for (int j = 0; j < 4; ++j) {
          float pv = __builtin_amdgcn_exp2f(s[j][r] - mn);
          rs += pv;
          pbuf[wave][(lg * 4 + r) * 72 + j * 16 + l15] = (f16)pv;
        }
        rs += __shfl_xor(rs, 1);
        rs += __shfl_xor(rs, 2);
        rs += __shfl_xor(rs, 4);
        rs += __shfl_xor(rs, 8);
        ll[r] = ll[r] * fac + rs;
#pragma unroll
        for (int n = 0; n < 8; ++n) o[n][r] *= fac;
      }
      __syncthreads();

#pragma unroll
      for (int kc = 0; kc < 2; ++kc) {
        f16x8 pa = *(const f16x8*)(&pbuf[wave][l15 * 72 + kc * 32 + lg * 8]);
#pragma unroll
        for (int n = 0; n < 8; ++n) {
          const int vrow = n * 16 + l15;
          f16x8 vv = *(const f16x8*)(sV + vrow * 64 + (((kc * 32 + lg * 8)) ^ ((vrow & 7) << 3)));
          o[n] = mfma16(pa, vv, o[n]);
        }
      }
      __syncthreads();
    }

#pragma unroll
    for (int r = 0; r < 4; ++r) {
      float inv = 1.0f / ll[r];
      long rbase = (long)(b * 1024 + qbase + lg * 4 + r) * 2048 + h * 128;
#pragma unroll
      for (int n = 0; n < 8; ++n)
        Ctx[rbase + n * 16 + l15] = (f16)(o[n][r] * inv);
    }
  }
}

// ---------------- launch ----------------
extern "C" void kernel_launch(void* const* d_in, const int* in_sizes, int n_in,
                              void* d_out, int out_size, void* d_ws, size_t ws_size,
                              hipStream_t stream) {
  (void)in_sizes; (void)n_in; (void)out_size; (void)ws_size;
  const float* x  = (const float*)d_in[0];
  const float* Wq = (const float*)d_in[1];
  const float* Wk = (const float*)d_in[2];
  const float* Wv = (const float*)d_in[3];
  const float* Wo = (const float*)d_in[4];
  float* out = (float*)d_out;
  f16* ws = (f16*)d_ws;

  const long MD = 4096L * 2048;   // x / q / k / v / ctx elements
  const long DD = 2048L * 2048;   // weight elements

  f16* xh  = ws;                  // [MD]
  f16* xl  = ws + MD;             // [MD]
  f16* wqh = ws + 2 * MD;         // [DD] x6 weights
  f16* wql = wqh + DD;
  f16* wkh = wql + DD;
  f16* wkl = wkh + DD;
  f16* wv  = wkl + DD;
  f16* wo  = wv + DD;
  f16* qh  = wo + DD;             // [MD] x4
  f16* ql  = qh + MD;
  f16* kh  = ql + MD;
  f16* kl  = kh + MD;
  f16* vt  = kl + MD;             // [MD] V^T
  f16* vh  = xl;                  // alias: V (plain), xl dead after K-proj
  f16* ctx = xh;                  // alias: ctx, xh dead after V-proj

  conv_split_k<<<8192, 256, 0, stream>>>(x,  xh,  xl,  (int)(MD / 4));
  conv_split_k<<<4096, 256, 0, stream>>>(Wq, wqh, wql, (int)(DD / 4));
  conv_split_k<<<4096, 256, 0, stream>>>(Wk, wkh, wkl, (int)(DD / 4));
  conv_plain_k<<<4096, 256, 0, stream>>>(Wv, wv, (int)(DD / 4));
  conv_plain_k<<<4096, 256, 0, stream>>>(Wo, wo, (int)(DD / 4));

  dim3 gg(16, 32);  // (N/128, M/128)
  gemm_split<<<gg, 256, 0, stream>>>(xh, xl, wqh, wql, qh, ql, 2048, 2048);
  gemm_split<<<gg, 256, 0, stream>>>(xh, xl, wkh, wkl, kh, kl, 2048, 2048);
  gemm_bt<0><<<gg, 256, 0, stream>>>(xh, wv, vh, 2048, 2048);
  transpose_v_k<<<dim3(16, 2, 64), 256, 0, stream>>>(vh, vt);
  attn_k<<<dim3(64, 8), 256, 0, stream>>>(qh, ql, kh, kl, vt, ctx);
  gemm_bt<2><<<gg, 256, 0, stream>>>(ctx, wo, out, 2048, 2048);
}